// Round 2
// baseline (267.291 us; speedup 1.0000x reference)
//
#include <hip/hip_runtime.h>

// out[b,f,d] = x[b,f] * W[f,d] + b[f,d]   (B=16384, F=64, D=192, fp32)
//
// Round-2 structure: each thread owns a FIXED output column j = f*48+c
// (j in [0,3072), float4 granularity), so W[j] and b[j] are loop-invariant
// registers. Thread iterates over a 64-batch chunk:
//   inner loop = 1 broadcast x read (4B) + 4 FMA + 1 coalesced 16B store.
// Grid: (12 j-chunks of 256 threads) x (256 batch chunks of 64).
// 3072 blocks, 64 iters/thread -> pure streaming-write regime.

__global__ __launch_bounds__(256) void ftemb_kernel(
    const float*  __restrict__ x,    // [B*64]
    const float4* __restrict__ W,    // [3072]  (64 x 48 float4)
    const float4* __restrict__ Bb,   // [3072]
    float4*       __restrict__ out)  // [B*3072]
{
    const int j  = blockIdx.x * 256 + threadIdx.x;  // 0..3071 = f*48 + c
    const int f  = j / 48;                          // feature of this column
    const int b0 = blockIdx.y * 64;                 // batch chunk base

    const float4 w  = W[j];   // loop-invariant, register-resident
    const float4 bb = Bb[j];

    const float*  xp = x   + (size_t)b0 * 64 + f;
    float4*       op = out + (size_t)b0 * 3072 + j;

    #pragma unroll 8
    for (int k = 0; k < 64; ++k) {
        float xs = xp[(size_t)k * 64];   // ~1-2 distinct dwords per wave
        float4 o;
        o.x = fmaf(xs, w.x, bb.x);
        o.y = fmaf(xs, w.y, bb.y);
        o.z = fmaf(xs, w.z, bb.z);
        o.w = fmaf(xs, w.w, bb.w);
        op[(size_t)k * 3072] = o;        // 16 B/lane, wave-contiguous 1 KB
    }
}

extern "C" void kernel_launch(void* const* d_in, const int* in_sizes, int n_in,
                              void* d_out, int out_size, void* d_ws, size_t ws_size,
                              hipStream_t stream) {
    const float*  x  = (const float*)d_in[0];
    const float4* W  = (const float4*)d_in[1];
    const float4* Bb = (const float4*)d_in[2];
    float4* out = (float4*)d_out;

    dim3 grid(12, 256);   // 12 x 256-thread j-chunks cover 3072 columns;
                          // 256 chunks x 64 batches cover B=16384
    dim3 block(256);
    ftemb_kernel<<<grid, block, 0, stream>>>(x, W, Bb, out);
}

// Round 4
// 174.523 us; speedup vs baseline: 1.5316x; 1.5316x over previous
//
#include <hip/hip_runtime.h>

// out[b,f,d] = x[b,f] * W[f,d] + b[f,d]   (B=16384, F=64, D=192, fp32)
//
// Round-4: round-1 flat grid-stride float4 sweep (best DRAM locality)
// + NONTEMPORAL stores (native ext_vector_type for the builtin) to bypass
// L2 write-allocate (the 2x-traffic theory).
// Reads (x, W, b) stay cached: W+b = 96 KB L2-resident, x reused 48x.

typedef float floatx4 __attribute__((ext_vector_type(4)));

__global__ __launch_bounds__(256) void ftemb_kernel(
    const float*   __restrict__ x,    // [B*64]
    const floatx4* __restrict__ W,    // [64*48]
    const floatx4* __restrict__ Bb,   // [64*48]
    floatx4*       __restrict__ out,  // [B*64*48]
    int total4)
{
    int i = blockIdx.x * blockDim.x + threadIdx.x;
    const int stride = gridDim.x * blockDim.x;
    for (; i < total4; i += stride) {
        int row = i / 48;              // b*64 + f  (magic-mul)
        int c   = i - row * 48;        // float4 column within row
        int f   = row & 63;
        float xs   = x[row];           // cached, reused 48x per row
        floatx4 w  = W[f * 48 + c];    // 96 KB W+b -> L2-resident
        floatx4 bb = Bb[f * 48 + c];
        floatx4 o;
        o.x = fmaf(xs, w.x, bb.x);
        o.y = fmaf(xs, w.y, bb.y);
        o.z = fmaf(xs, w.z, bb.z);
        o.w = fmaf(xs, w.w, bb.w);
        __builtin_nontemporal_store(o, &out[i]);   // global_store_dwordx4 ... nt
    }
}

extern "C" void kernel_launch(void* const* d_in, const int* in_sizes, int n_in,
                              void* d_out, int out_size, void* d_ws, size_t ws_size,
                              hipStream_t stream) {
    const float*   x  = (const float*)d_in[0];
    const floatx4* W  = (const floatx4*)d_in[1];
    const floatx4* Bb = (const floatx4*)d_in[2];
    floatx4* out = (floatx4*)d_out;

    const int total4 = out_size / 4;   // 50,331,648
    const int threads = 256;
    const int blocks  = 2048;          // grid-stride, 96 iters/thread
    ftemb_kernel<<<blocks, threads, 0, stream>>>(x, W, Bb, out, total4);
}

// Round 5
// 144.829 us; speedup vs baseline: 1.8456x; 1.2050x over previous
//
#include <hip/hip_runtime.h>

// out[b,f,d] = x[b,f] * W[f,d] + b[f,d]   (B=16384, F=64, D=192, fp32)
//
// Round-5: column-fixed threads (W[j], b[j] loop-invariant in registers;
// round-2 structure) + nontemporal stores (round-4 win). Inner loop is
// 1 broadcast 4B x read + 4 FMA + 1 contiguous 16B NT store per lane.
// Per wave-iteration: ~8 B of L1 reads per 1 KB stored -> store stream
// owns the L1/TA pipe; HBM write floor (~120-130 us) should be the limit.

typedef float floatx4 __attribute__((ext_vector_type(4)));

__global__ __launch_bounds__(256) void ftemb_kernel(
    const float*   __restrict__ x,    // [B*64]
    const floatx4* __restrict__ W,    // [3072] = 64 x 48
    const floatx4* __restrict__ Bb,   // [3072]
    floatx4*       __restrict__ out)  // [B*3072]
{
    const int j  = blockIdx.x * 256 + threadIdx.x;  // 0..3071 = f*48 + c
    const int f  = j / 48;
    const int b0 = blockIdx.y * 64;                 // batch chunk base

    const floatx4 w  = W[j];    // register-resident for all 64 iterations
    const floatx4 bb = Bb[j];

    const float* xp = x   + (size_t)b0 * 64 + f;
    floatx4*     op = out + (size_t)b0 * 3072 + j;

    #pragma unroll 8
    for (int k = 0; k < 64; ++k) {
        float xs = xp[(size_t)k * 64];   // ~2 distinct dwords per wave (broadcast)
        floatx4 o;
        o.x = fmaf(xs, w.x, bb.x);
        o.y = fmaf(xs, w.y, bb.y);
        o.z = fmaf(xs, w.z, bb.z);
        o.w = fmaf(xs, w.w, bb.w);
        __builtin_nontemporal_store(o, &op[(size_t)k * 3072]);  // 1 KB/wave burst
    }
}

extern "C" void kernel_launch(void* const* d_in, const int* in_sizes, int n_in,
                              void* d_out, int out_size, void* d_ws, size_t ws_size,
                              hipStream_t stream) {
    const float*   x  = (const float*)d_in[0];
    const floatx4* W  = (const floatx4*)d_in[1];
    const floatx4* Bb = (const floatx4*)d_in[2];
    floatx4* out = (floatx4*)d_out;

    dim3 grid(12, 256);   // 12 j-chunks x 256 batch chunks; 3072 blocks, 64 iters
    dim3 block(256);
    ftemb_kernel<<<grid, block, 0, stream>>>(x, W, Bb, out);
}

// Round 6
// 142.725 us; speedup vs baseline: 1.8728x; 1.0147x over previous
//
#include <hip/hip_runtime.h>

// out[b,f,d] = x[b,f] * W[f,d] + b[f,d]   (B=16384, F=64, D=192, fp32)
//
// Round-6: column-fixed threads (W/b register-resident) + NT stores
// + x staged in LDS so the inner loop's only wait is lgkmcnt (ds_read),
// never vmcnt -> NT stores stream fire-and-forget with no drain stalls.
// LDS: 64 batches x 64 feats x 4B = 16 KB per block.

typedef float floatx4 __attribute__((ext_vector_type(4)));

__global__ __launch_bounds__(256) void ftemb_kernel(
    const float*   __restrict__ x,    // [B*64]
    const floatx4* __restrict__ W,    // [3072] = 64 feats x 48
    const floatx4* __restrict__ Bb,   // [3072]
    floatx4*       __restrict__ out)  // [B*3072]
{
    __shared__ floatx4 xs_lds[1024];               // 64x64 floats = 16 KB

    const int tid = threadIdx.x;
    const int j   = blockIdx.x * 256 + tid;        // 0..3071 = f*48 + c
    const int f   = j / 48;
    const int b0  = blockIdx.y * 64;               // batch chunk base

    const floatx4 w  = W[j];                       // loop-invariant registers
    const floatx4 bb = Bb[j];

    // Stage x[b0..b0+63][0..63] (contiguous 16 KB) into LDS: 4 float4/thread.
    const floatx4* xsrc = (const floatx4*)(x + (size_t)b0 * 64);
    #pragma unroll
    for (int t = 0; t < 4; ++t)
        xs_lds[t * 256 + tid] = xsrc[t * 256 + tid];
    __syncthreads();

    const float* xf = (const float*)xs_lds;
    floatx4* op = out + (size_t)b0 * 3072 + j;

    #pragma unroll 8
    for (int k = 0; k < 64; ++k) {
        float xs = xf[k * 64 + f];                 // ds_read (lgkmcnt path)
        floatx4 o;
        o.x = fmaf(xs, w.x, bb.x);
        o.y = fmaf(xs, w.y, bb.y);
        o.z = fmaf(xs, w.z, bb.z);
        o.w = fmaf(xs, w.w, bb.w);
        __builtin_nontemporal_store(o, &op[(size_t)k * 3072]);  // never waited
    }
}

extern "C" void kernel_launch(void* const* d_in, const int* in_sizes, int n_in,
                              void* d_out, int out_size, void* d_ws, size_t ws_size,
                              hipStream_t stream) {
    const float*   x  = (const float*)d_in[0];
    const floatx4* W  = (const floatx4*)d_in[1];
    const floatx4* Bb = (const floatx4*)d_in[2];
    floatx4* out = (floatx4*)d_out;

    dim3 grid(12, 256);   // 12 j-chunks x 256 batch chunks
    dim3 block(256);
    ftemb_kernel<<<grid, block, 0, stream>>>(x, W, Bb, out);
}